// Round 9
// baseline (175.423 us; speedup 1.0000x reference)
//
#include <hip/hip_runtime.h>
#include <math.h>

#define N_RES 4096
#define KNB 32
#define BN_TOTAL 65536  // B*N = 16*4096

typedef float v4f __attribute__((ext_vector_type(4)));
typedef int v4i __attribute__((ext_vector_type(4)));

// Wave-private LDS layout (floats), chunk = 16 neighbors of the wave's 8 elems.
#define ROT_S 148                    // 144 + 4 pad: read bank = (20e+9t+..)%32 -> <=2-way (free)
#define TRN_S 52                     // 48 + 4 pad:  read bank = (20e+3t+..)%32 -> <=2-way (free)
#define TRN_BASE (8 * ROT_S)         // 1184
#define WLDS (TRN_BASE + 8 * TRN_S)  // 1600 floats = 6.4KB per wave

// ---------------------------------------------------------------------------
// SO(3) projection (cyclic Jacobi on M^T M + Gram-Schmidt for U) — validated.
// ---------------------------------------------------------------------------
template <int p, int q>
__device__ __forceinline__ void jacobi_rot(float S[3][3], float V[3][3]) {
    float apq = S[p][q];
    if (fabsf(apq) > 1e-20f) {
        float app = S[p][p], aqq = S[q][q];
        float tau = (aqq - app) / (2.0f * apq);
        float tt = (tau >= 0.0f ? 1.0f : -1.0f) / (fabsf(tau) + sqrtf(1.0f + tau * tau));
        float c = 1.0f / sqrtf(1.0f + tt * tt);
        float s = tt * c;
#pragma unroll
        for (int i = 0; i < 3; i++) {
            float Sip = S[i][p], Siq = S[i][q];
            S[i][p] = c * Sip - s * Siq;
            S[i][q] = s * Sip + c * Siq;
        }
#pragma unroll
        for (int i = 0; i < 3; i++) {
            float Spi = S[p][i], Sqi = S[q][i];
            S[p][i] = c * Spi - s * Sqi;
            S[q][i] = s * Spi + c * Sqi;
        }
#pragma unroll
        for (int i = 0; i < 3; i++) {
            float Vip = V[i][p], Viq = V[i][q];
            V[i][p] = c * Vip - s * Viq;
            V[i][q] = s * Vip + c * Viq;
        }
    }
}

template <int A, int Bc>
__device__ __forceinline__ void sort_pair(float lam[3], float V[3][3]) {
    if (lam[A] < lam[Bc]) {
        float tl = lam[A]; lam[A] = lam[Bc]; lam[Bc] = tl;
#pragma unroll
        for (int i = 0; i < 3; i++) {
            float tv = V[i][A]; V[i][A] = V[i][Bc]; V[i][Bc] = tv;
        }
    }
}

__device__ __forceinline__ void project_and_store(const float M[3][3],
                                                  float t0, float t1, float t2,
                                                  float* outp) {
    float S[3][3];
#pragma unroll
    for (int i = 0; i < 3; i++)
#pragma unroll
        for (int j = 0; j < 3; j++)
            S[i][j] = M[0][i] * M[0][j] + M[1][i] * M[1][j] + M[2][i] * M[2][j];
    float V[3][3] = {{1, 0, 0}, {0, 1, 0}, {0, 0, 1}};

#pragma unroll
    for (int sweep = 0; sweep < 4; sweep++) {
        jacobi_rot<0, 1>(S, V);
        jacobi_rot<0, 2>(S, V);
        jacobi_rot<1, 2>(S, V);
    }

    float lam[3] = {S[0][0], S[1][1], S[2][2]};
    sort_pair<0, 1>(lam, V);
    sort_pair<1, 2>(lam, V);
    sort_pair<0, 1>(lam, V);

    float detV = V[0][0] * (V[1][1] * V[2][2] - V[1][2] * V[2][1]) -
                 V[0][1] * (V[1][0] * V[2][2] - V[1][2] * V[2][0]) +
                 V[0][2] * (V[1][0] * V[2][1] - V[1][1] * V[2][0]);
    if (detV < 0.0f) { V[0][2] = -V[0][2]; V[1][2] = -V[1][2]; V[2][2] = -V[2][2]; }

    float Bm[3][3];
#pragma unroll
    for (int i = 0; i < 3; i++)
#pragma unroll
        for (int j = 0; j < 3; j++)
            Bm[i][j] = M[i][0] * V[0][j] + M[i][1] * V[1][j] + M[i][2] * V[2][j];

    float u0[3] = {Bm[0][0], Bm[1][0], Bm[2][0]};
    float n0 = u0[0] * u0[0] + u0[1] * u0[1] + u0[2] * u0[2];
    float rn0 = 1.0f / sqrtf(fmaxf(n0, 1e-24f));
    u0[0] *= rn0; u0[1] *= rn0; u0[2] *= rn0;

    float b1[3] = {Bm[0][1], Bm[1][1], Bm[2][1]};
    float d01 = u0[0] * b1[0] + u0[1] * b1[1] + u0[2] * b1[2];
    float u1[3] = {b1[0] - d01 * u0[0], b1[1] - d01 * u0[1], b1[2] - d01 * u0[2]};
    float n1 = u1[0] * u1[0] + u1[1] * u1[1] + u1[2] * u1[2];
    float rn1 = 1.0f / sqrtf(fmaxf(n1, 1e-24f));
    u1[0] *= rn1; u1[1] *= rn1; u1[2] *= rn1;

    float u2[3] = {u0[1] * u1[2] - u0[2] * u1[1],
                   u0[2] * u1[0] - u0[0] * u1[2],
                   u0[0] * u1[1] - u0[1] * u1[0]};

    float R[9];
#pragma unroll
    for (int i = 0; i < 3; i++) {
        float Ui0 = (i == 0 ? u0[0] : (i == 1 ? u0[1] : u0[2]));
        float Ui1 = (i == 0 ? u1[0] : (i == 1 ? u1[1] : u1[2]));
        float Ui2 = (i == 0 ? u2[0] : (i == 1 ? u2[1] : u2[2]));
#pragma unroll
        for (int j = 0; j < 3; j++)
            R[i * 3 + j] = Ui0 * V[j][0] + Ui1 * V[j][1] + Ui2 * V[j][2];
    }

    v4f* o4 = (v4f*)outp;
    o4[0] = (v4f){R[0], R[1], R[2], R[3]};
    o4[1] = (v4f){R[4], R[5], R[6], R[7]};
    o4[2] = (v4f){R[8], t0, t1, t2};
}

// ---------------------------------------------------------------------------
// Kernel 1: repack frames -> fp32, one 64B row per residue:
// [r0..r8, t0..t2, pad*4]. (fp16 failed R6: Kabsch amplifies rot error ~100x.)
// ---------------------------------------------------------------------------
__global__ __launch_bounds__(256) void repack_kernel(
    const float* __restrict__ frames_rot,    // [B*N, 9]
    const float* __restrict__ frames_trans,  // [B*N, 3]
    float* __restrict__ pk)                  // [B*N, 16]
{
    int row = blockIdx.x * 256 + threadIdx.x;
    const float* fr = frames_rot + (size_t)row * 9;
    const float* ft = frames_trans + (size_t)row * 3;
    v4f* o = (v4f*)(pk + (size_t)row * 16);
    o[0] = (v4f){fr[0], fr[1], fr[2], fr[3]};
    o[1] = (v4f){fr[4], fr[5], fr[6], fr[7]};
    o[2] = (v4f){fr[8], ft[0], ft[1], ft[2]};
}

// ---------------------------------------------------------------------------
// Kernel 2: barrier-free, pipe-balanced accumulation.
// One wave = 8 elems; lane L: e = L>>3, t = L&7 owns neighbors {t+8s, s=0..3}
// (serial accumulate -> butterfly only over strides 1/2/4 = 39 cross-lane ops
// per 8 elems, DPP-eligible). Streams staged coalesced into WAVE-PRIVATE LDS
// in 2 chunks of 16 neighbors (6.4KB/wave, no __syncthreads anywhere; wave-
// synchronous lgkmcnt orders write->read). Pad strides 148/52 give <=2-way
// (free) LDS banking on the strided record reads.
// R8 (32 lanes/elem) was LDS/cross-lane-pipe bound: 65 swizzles + 12 ds_read
// per wave covering only 2 elems ~= 25us of LDS pipe. This shape cuts the
// reduction to 4.9 ops/elem and LDS pipe to ~6us while keeping all of R8's
// barrier-free overlap.
//
// NOTE: NO min-waves pin. R4's __launch_bounds__(256,8) capped VGPRs at 32
// -> scratch spills -> +178MB HBM writes. Live set needs ~70-90 VGPRs.
// ---------------------------------------------------------------------------
__global__ __launch_bounds__(256) void accum_kernel(
    const float* __restrict__ pk,         // [B*N,16] packed fp32 frames
    const float* __restrict__ pair_rot,   // [B,N,K,9]
    const float* __restrict__ pair_trans, // [B,N,K,3]
    const float* __restrict__ conf,       // [B,N,K]
    const int* __restrict__ topo,         // [B,N,K]
    float* __restrict__ acc)              // [B*N,16]
{
    __shared__ float lds[4 * WLDS];  // 4 waves x 6.4KB = 25.6KB -> 6 blk/CU

    int tid = threadIdx.x;
    int wid = tid >> 6;   // wave in block 0..3
    int L = tid & 63;     // lane in wave
    int bid = blockIdx.x; // 0..2047

    // XCD-pinned batch swizzle: XCD x serves batches {x, x+8} -> pk slice
    // (2 x 256KB) stays L2-resident per XCD.
    int xcd = bid & 7;
    int slot = bid >> 3;                    // 0..255
    int batch = xcd + ((slot >> 7) << 3);   // 0..15
    int within = slot & 127;                // 0..127
    int elem0 = batch * N_RES + within * 32 + wid * 8;  // wave's first elem

    int e = L >> 3;       // elem-in-wave 0..7
    int t = L & 7;        // lane-in-elem 0..7
    int elem_g = elem0 + e;

    float* wlds = lds + wid * WLDS;

    // --- conf/topo for the 4 owned neighbors {t+8s}: 8-wide segments. ---
    float wl[4];
    int jl[4];
#pragma unroll
    for (int s = 0; s < 4; s++) {
        size_t nidx = (size_t)elem_g * KNB + s * 8 + t;
        wl[s] = __builtin_nontemporal_load(conf + nidx);
        jl[s] = __builtin_nontemporal_load(topo + nidx);
    }

    // --- Gather pipeline: 2 frame rows in flight (3 x dwordx4 each). ---
    const float* pkb = pk + (size_t)batch * N_RES * 16;
    v4f g0a, g0b, g0c, g1a, g1b, g1c;
    {
        const v4f* r0 = (const v4f*)(pkb + (size_t)jl[0] * 16);
        const v4f* r1 = (const v4f*)(pkb + (size_t)jl[1] * 16);
        g0a = r0[0]; g0b = r0[1]; g0c = r0[2];
        g1a = r1[0]; g1b = r1[1]; g1c = r1[2];
    }

    const v4f* rg = (const v4f*)(pair_rot + (size_t)elem0 * (KNB * 9));
    const v4f* tg = (const v4f*)(pair_trans + (size_t)elem0 * (KNB * 3));

    float Macc[9] = {0, 0, 0, 0, 0, 0, 0, 0, 0};
    float tacc[3] = {0, 0, 0};
    float wsum = wl[0] + wl[1] + wl[2] + wl[3];

#pragma unroll
    for (int ch = 0; ch < 2; ch++) {
        // --- Stage rot chunk: 8 elems x 16 nbrs x 9 f = 288 v4f, coalesced.
        for (int i = L; i < 288; i += 64) {
            int e2 = i / 36;
            int r = i - e2 * 36;
            v4f v = __builtin_nontemporal_load(rg + e2 * 72 + ch * 36 + r);
            *(v4f*)(wlds + e2 * ROT_S + 4 * r) = v;
        }
        // --- Stage trans chunk: 8 elems x 16 nbrs x 3 f = 96 v4f.
        for (int i = L; i < 96; i += 64) {
            int e2 = i / 12;
            int r = i - e2 * 12;
            v4f v = __builtin_nontemporal_load(tg + e2 * 24 + ch * 12 + r);
            *(v4f*)(wlds + TRN_BASE + e2 * TRN_S + 4 * r) = v;
        }
        // No barrier: wave-synchronous LDS, compiler lgkmcnt orders write->read.

        // --- Compute the chunk's 2 owned neighbors (s = 2ch, 2ch+1). ---
#pragma unroll
        for (int sc = 0; sc < 2; sc++) {
            int s = 2 * ch + sc;
            float w = wl[s];
            int m = sc * 8 + t;  // neighbor within chunk 0..15
            const float* lp = wlds + e * ROT_S + 9 * m;
            float p[9];
#pragma unroll
            for (int c = 0; c < 9; c++) p[c] = lp[c];
            const float* tp = wlds + TRN_BASE + e * TRN_S + 3 * m;
            float q0 = tp[0], q1 = tp[1], q2 = tp[2];

            v4f fa = (s & 1) ? g1a : g0a;
            v4f fb = (s & 1) ? g1b : g0b;
            v4f fc = (s & 1) ? g1c : g0c;
            float r[9] = {fa.x, fa.y, fa.z, fa.w, fb.x, fb.y, fb.z, fb.w, fc.x};
            float tj[3] = {fc.y, fc.z, fc.w};

#pragma unroll
            for (int i = 0; i < 3; i++) {
#pragma unroll
                for (int l = 0; l < 3; l++) {
                    Macc[i * 3 + l] += w * (r[i * 3 + 0] * p[0 * 3 + l] +
                                            r[i * 3 + 1] * p[1 * 3 + l] +
                                            r[i * 3 + 2] * p[2 * 3 + l]);
                }
                tacc[i] += w * (r[i * 3 + 0] * q0 + r[i * 3 + 1] * q1 +
                                r[i * 3 + 2] * q2 + tj[i]);
            }

            // Refill consumed gather slot for chunk 1.
            if (ch == 0) {
                const v4f* rn = (const v4f*)(pkb + (size_t)jl[2 + sc] * 16);
                if (sc == 0) { g0a = rn[0]; g0b = rn[1]; g0c = rn[2]; }
                else         { g1a = rn[0]; g1b = rn[1]; g1c = rn[2]; }
            }
        }
    }

    // --- Butterfly over the 8 consecutive lanes of this elem (DPP strides).
#pragma unroll
    for (int st = 1; st <= 4; st <<= 1) {
#pragma unroll
        for (int i = 0; i < 9; i++) Macc[i] += __shfl_xor(Macc[i], st);
#pragma unroll
        for (int i = 0; i < 3; i++) tacc[i] += __shfl_xor(tacc[i], st);
        wsum += __shfl_xor(wsum, st);
    }

    if (t == 0) {
        v4f* o = (v4f*)(acc + (size_t)elem_g * 16);
        o[0] = (v4f){Macc[0], Macc[1], Macc[2], Macc[3]};
        o[1] = (v4f){Macc[4], Macc[5], Macc[6], Macc[7]};
        o[2] = (v4f){Macc[8], tacc[0], tacc[1], tacc[2]};
        o[3] = (v4f){wsum, 0.0f, 0.0f, 0.0f};
    }
}

// ---------------------------------------------------------------------------
// Kernel 3: per-element SO(3) solve, 1 thread/elem (dense, no redundancy).
// ---------------------------------------------------------------------------
__global__ __launch_bounds__(256) void solve_kernel(
    const float* __restrict__ acc,  // [B*N,16]
    float* __restrict__ out)        // [B*N,12]
{
    int elem = blockIdx.x * 256 + threadIdx.x;
    const v4f* a4 = (const v4f*)(acc + (size_t)elem * 16);
    v4f A0 = a4[0], A1 = a4[1], A2 = a4[2], A3 = a4[3];
    float inv_w = 1.0f / fmaxf(A3.x, 1e-20f);
    float M[3][3] = {{A0.x * inv_w, A0.y * inv_w, A0.z * inv_w},
                     {A0.w * inv_w, A1.x * inv_w, A1.y * inv_w},
                     {A1.z * inv_w, A1.w * inv_w, A2.x * inv_w}};
    float t0 = A2.y * inv_w, t1 = A2.z * inv_w, t2 = A2.w * inv_w;
    project_and_store(M, t0, t1, t2, out + (size_t)elem * 12);
}

// ---------------------------------------------------------------------------
// Fallback fused kernel (only if ws too small) — Round-2 validated path.
// ---------------------------------------------------------------------------
__global__ __launch_bounds__(256) void fused_kernel(
    const float* __restrict__ frames_rot, const float* __restrict__ frames_trans,
    const float* __restrict__ pair_rot, const float* __restrict__ pair_trans,
    const float* __restrict__ conf, const int* __restrict__ topo,
    float* __restrict__ out)
{
    int tid = threadIdx.x;
    int bid = blockIdx.x;
    int xcd = bid & 7;
    int slot = bid >> 3;
    int batch = xcd + ((slot >> 7) << 3);
    int chunk = slot & 127;
    int elem = batch * N_RES + chunk * 32 + (tid >> 3);
    int t = tid & 7;

    const float* fr_b = frames_rot + (size_t)batch * N_RES * 9;
    const float* ft_b = frames_trans + (size_t)batch * N_RES * 3;

    size_t kbase = (size_t)elem * KNB + (size_t)t * 4;
    const v4f* pr4 = (const v4f*)(pair_rot + kbase * 9);
    const v4f* pt4 = (const v4f*)(pair_trans + kbase * 3);
    const v4f* cf4 = (const v4f*)(conf + kbase);
    const v4i* tp4 = (const v4i*)(topo + kbase);

    float prl[36];
#pragma unroll
    for (int i = 0; i < 9; i++) {
        v4f v = __builtin_nontemporal_load(pr4 + i);
        prl[4 * i] = v.x; prl[4 * i + 1] = v.y; prl[4 * i + 2] = v.z; prl[4 * i + 3] = v.w;
    }
    float ptl[12];
#pragma unroll
    for (int i = 0; i < 3; i++) {
        v4f v = __builtin_nontemporal_load(pt4 + i);
        ptl[4 * i] = v.x; ptl[4 * i + 1] = v.y; ptl[4 * i + 2] = v.z; ptl[4 * i + 3] = v.w;
    }
    v4f wv = __builtin_nontemporal_load(cf4);
    float wl[4] = {wv.x, wv.y, wv.z, wv.w};
    v4i jv = __builtin_nontemporal_load(tp4);
    int jl[4] = {jv.x, jv.y, jv.z, jv.w};

    float Macc[9] = {0, 0, 0, 0, 0, 0, 0, 0, 0};
    float tacc[3] = {0, 0, 0};
    float wsum = 0.0f;

#pragma unroll
    for (int kk = 0; kk < 4; kk++) {
        int j = jl[kk];
        const float* Rj = fr_b + j * 9;
        const float* Tj = ft_b + j * 3;
        float r[9];
#pragma unroll
        for (int i = 0; i < 9; i++) r[i] = Rj[i];
        float tj[3];
#pragma unroll
        for (int i = 0; i < 3; i++) tj[i] = Tj[i];
        float w = wl[kk];
        const float* pr = prl + kk * 9;
        const float* pt = ptl + kk * 3;
#pragma unroll
        for (int i = 0; i < 3; i++) {
#pragma unroll
            for (int l = 0; l < 3; l++) {
                float cij = r[i * 3] * pr[l] + r[i * 3 + 1] * pr[3 + l] + r[i * 3 + 2] * pr[6 + l];
                Macc[i * 3 + l] += w * cij;
            }
            float ct = r[i * 3] * pt[0] + r[i * 3 + 1] * pt[1] + r[i * 3 + 2] * pt[2] + tj[i];
            tacc[i] += w * ct;
        }
        wsum += w;
    }

#pragma unroll
    for (int st = 1; st <= 4; st <<= 1) {
#pragma unroll
        for (int i = 0; i < 9; i++) Macc[i] += __shfl_xor(Macc[i], st);
#pragma unroll
        for (int i = 0; i < 3; i++) tacc[i] += __shfl_xor(tacc[i], st);
        wsum += __shfl_xor(wsum, st);
    }

    float inv_w = 1.0f / fmaxf(wsum, 1e-20f);
    float M[3][3];
#pragma unroll
    for (int i = 0; i < 3; i++)
#pragma unroll
        for (int j = 0; j < 3; j++) M[i][j] = Macc[i * 3 + j] * inv_w;

    if (t == 0)
        project_and_store(M, tacc[0] * inv_w, tacc[1] * inv_w, tacc[2] * inv_w,
                          out + (size_t)elem * 12);
}

extern "C" void kernel_launch(void* const* d_in, const int* in_sizes, int n_in,
                              void* d_out, int out_size, void* d_ws, size_t ws_size,
                              hipStream_t stream) {
    const float* frames_rot = (const float*)d_in[0];
    const float* frames_trans = (const float*)d_in[1];
    const float* pair_rot = (const float*)d_in[2];
    const float* pair_trans = (const float*)d_in[3];
    const float* conf = (const float*)d_in[4];
    const int* topo = (const int*)d_in[5];
    float* out = (float*)d_out;

    const size_t PK_BYTES = (size_t)BN_TOTAL * 16 * sizeof(float);   // 4MB
    const size_t ACC_BYTES = (size_t)BN_TOTAL * 16 * sizeof(float);  // 4MB
    const size_t need = PK_BYTES + ACC_BYTES;                        // 8MB

    if (ws_size >= need) {
        float* pk = (float*)d_ws;
        float* acc = (float*)((char*)d_ws + PK_BYTES);
        hipLaunchKernelGGL(repack_kernel, dim3(BN_TOTAL / 256), dim3(256), 0, stream,
                           frames_rot, frames_trans, pk);
        // one wave per 8 elems, 4 waves/block -> 65536 / 32 = 2048 blocks
        hipLaunchKernelGGL(accum_kernel, dim3(BN_TOTAL / 32), dim3(256), 0, stream,
                           pk, pair_rot, pair_trans, conf, topo, acc);
        hipLaunchKernelGGL(solve_kernel, dim3(BN_TOTAL / 256), dim3(256), 0, stream,
                           acc, out);
    } else {
        hipLaunchKernelGGL(fused_kernel, dim3(BN_TOTAL * 8 / 256), dim3(256), 0, stream,
                           frames_rot, frames_trans, pair_rot, pair_trans, conf, topo, out);
    }
}